// Round 20
// baseline (269.413 us; speedup 1.0000x reference)
//
#include <hip/hip_runtime.h>
#include <math.h>

#define DIMX 50
#define KK   51
#define NE   6
#define NB   8
#define NVOX ((size_t)NB * NE * DIMX * DIMX * DIMX)  // 6,000,000

typedef short bf16x8 __attribute__((ext_vector_type(8)));
typedef float f32x4  __attribute__((ext_vector_type(4)));

__device__ __forceinline__ unsigned short f2bf(float f) {
    unsigned u = __float_as_uint(f);
    u += 0x7fffu + ((u >> 16) & 1u);      // RNE; inputs finite
    return (unsigned short)(u >> 16);
}
__device__ __forceinline__ float bf2f(unsigned short h) {
    return __uint_as_float((unsigned)h << 16);
}
__device__ __forceinline__ uint4 pack8(const unsigned short v[8]) {
    uint4 q;
    q.x = v[0] | ((unsigned)v[1] << 16);
    q.y = v[2] | ((unsigned)v[3] << 16);
    q.z = v[4] | ((unsigned)v[5] << 16);
    q.w = v[6] | ((unsigned)v[7] << 16);
    return q;
}
// truncation split of two floats -> packed hi-bf16 pair + lo-bf16 pair (6 VALU ops).
__device__ __forceinline__ void split2(float v0, float v1, unsigned& hp, unsigned& lp) {
    unsigned u0 = __float_as_uint(v0), u1 = __float_as_uint(v1);
    float h0 = __uint_as_float(u0 & 0xffff0000u);
    float h1 = __uint_as_float(u1 & 0xffff0000u);
    hp = __builtin_amdgcn_perm(u1, u0, 0x07060302u);
    lp = __builtin_amdgcn_perm(__float_as_uint(v1 - h1), __float_as_uint(v0 - h0), 0x07060302u);
}
// local (per-oyt) A-side fragment offset: kc=(k>>5), lane=((k>>3)&3)*16+(o&15), j=k&7
__device__ __forceinline__ int offA2(int o, int k) {
    return ((((k >> 5) * 64) + ((k >> 3) & 3) * 16 + (o & 15)) << 3) + (k & 7);
}

// -------- taps + MFMA-fragment-packed blur matrices --------
// MA[hl][e][t][kc][l][j]: A-side frags of RAW taps (own=o, k=z), val=tap[z-o+25]
// MB[hl][e][t][kc][l][j]: B-side frags of SCALED taps (own=ox, k=x), val=stap[x-ox+25]
__global__ void taps_kernel(const float* __restrict__ sigma,
                            unsigned short* __restrict__ MA, unsigned short* __restrict__ MB,
                            float* __restrict__ maxval) {
    __shared__ float sg[NE * KK];
    __shared__ float sgs[NE * KK];
    __shared__ float ssum[NE];
    int t = threadIdx.x;
    if (t == 0) *maxval = 0.f;
    if (t < NE * KK) {
        int e = t / KK, i = t % KK;
        float d = (float)i - 25.0f;
        float var = sigma[e] * sigma[e];
        sg[t] = expf(-d * d / (2.f * var));
    }
    __syncthreads();
    if (t < NE) {
        float s = 0.f;
        for (int i = 0; i < KK; ++i) s += sg[t * KK + i];
        ssum[t] = s;
    }
    __syncthreads();
    if (t < NE * KK) {
        int e = t / KK;
        float S = 0.f;
        for (int e2 = 0; e2 < NE; ++e2) {
            float var2 = sigma[e2] * sigma[e2];
            float a2 = 1.f / (2.f * (float)M_PI * var2);
            float se = ssum[e2];
            S += a2 * se * se * se;
        }
        float var = sigma[e] * sigma[e];
        float a = 1.f / (2.f * (float)M_PI * var);
        sgs[t] = sg[t] * (a / S);
    }
    __syncthreads();
    const int TOT = 2 * 6 * 4 * 2 * 64 * 8;   // 49152 per matrix
    for (int i = t; i < 2 * TOT; i += 512) {
        int which = i / TOT;                   // 0=MA(raw) 1=MB(scaled)
        int r = i % TOT;
        int q = r;
        int j = q & 7; q >>= 3;
        int l = q & 63; q >>= 6;
        int kc = q & 1; q >>= 1;
        int tile = q & 3; q >>= 2;
        int e = q % 6; q /= 6;
        int hl = q;                            // 0=hi 1=lo
        int own = tile * 16 + (l & 15);
        int k   = kc * 32 + ((l >> 4) << 3) + j;
        float v = 0.f;
        if (own < 50 && k < 50) {
            int d = k - own + 25;
            if (d >= 0 && d < KK) v = (which == 0 ? sg : sgs)[e * KK + d];
        }
        unsigned short h = f2bf(v);
        unsigned short out = (hl == 0) ? h : f2bf(v - bf2f(h));
        (which == 0 ? MA : MB)[r] = out;
    }
}

// -------- K1: z-axis blur via MFMA; 1-wave blocks, block = one xt strip, no LDS --------
__global__ __launch_bounds__(64)
void blur_k1(const float* __restrict__ in, float* __restrict__ W1,
             const unsigned short* __restrict__ MA) {
    const int l = threadIdx.x, lm = l & 15, lg = l >> 4;
    const int xt = (int)blockIdx.x & 3;
    const int r = (int)blockIdx.x >> 2;
    const int y = r % 50, be = r / 50, e = be % 6;
    const float* pb = in + (size_t)be * 125000 + y * 50;
    float* ob = W1 + (size_t)be * 125000 + y * 50;
    const f32x4 z4 = {0.f, 0.f, 0.f, 0.f};
    const int xx = xt * 16 + lm;
    bf16x8 bh[2], bl[2];
#pragma unroll
    for (int kc = 0; kc < 2; ++kc) {
        float v[8];
#pragma unroll
        for (int j = 0; j < 8; ++j) {
            int z = kc * 32 + lg * 8 + j;
            v[j] = (z < 50 && xx < 50) ? pb[(size_t)z * 2500 + xx] : 0.f;
        }
        uint4 qh, ql;
        split2(v[0], v[1], qh.x, ql.x);
        split2(v[2], v[3], qh.y, ql.y);
        split2(v[4], v[5], qh.z, ql.z);
        split2(v[6], v[7], qh.w, ql.w);
        bh[kc] = *(bf16x8*)&qh; bl[kc] = *(bf16x8*)&ql;
    }
#pragma unroll
    for (int ozt = 0; ozt < 4; ++ozt) {
        f32x4 acc = z4;
#pragma unroll
        for (int kc = 0; kc < 2; ++kc) {
            bf16x8 Ah = *(const bf16x8*)(MA + (((size_t)(0 * 6 + e) * 4 + ozt) * 2 + kc) * 512 + l * 8);
            bf16x8 Al = *(const bf16x8*)(MA + (((size_t)(1 * 6 + e) * 4 + ozt) * 2 + kc) * 512 + l * 8);
            acc = __builtin_amdgcn_mfma_f32_16x16x32_bf16(Ah, bh[kc], acc, 0, 0, 0);
            acc = __builtin_amdgcn_mfma_f32_16x16x32_bf16(Ah, bl[kc], acc, 0, 0, 0);
            acc = __builtin_amdgcn_mfma_f32_16x16x32_bf16(Al, bh[kc], acc, 0, 0, 0);
        }
        if (xx < 50) {
#pragma unroll
            for (int i = 0; i < 4; ++i) {
                int oz = ozt * 16 + lg * 4 + i;
                if (oz < 50) ob[(size_t)oz * 2500 + xx] = acc[i];
            }
        }
    }
}

// -------- K2: fused y-blur + x-blur(scaled) + max; 1-wave blocks, block = one oyt --------
// Q exchange is intra-oyt (4 KB LDS). Grid logical [(b,z)][e][oyt], bijective XCD swizzle
// (grid%8==0, 24-block (e,oyt)-groups never straddle chunks).
__global__ __launch_bounds__(64)
void blur_k2(const float* __restrict__ W1, const unsigned short* __restrict__ MA,
             const unsigned short* __restrict__ MB, unsigned short* __restrict__ X1,
             float* __restrict__ maxval) {
    __shared__ unsigned short Qhi[1024], Qlo[1024];
    const int l = threadIdx.x, lm = l & 15, lg = (l >> 4);
    const int q8 = (int)(gridDim.x >> 3);
    const int logical = ((int)blockIdx.x & 7) * q8 + ((int)blockIdx.x >> 3);
    const int oyt = logical & 3;
    const int r = logical >> 2;
    const int e = r % 6, bz = r / 6, z = bz % 50, b = bz / 50;
    const float* pb = W1 + (size_t)(b * 6 + e) * 125000 + (size_t)z * 2500;
    // full plane B fragments in registers
    bf16x8 Bh[4][2], Bl[4][2];
#pragma unroll
    for (int xt = 0; xt < 4; ++xt) {
        const int xx = xt * 16 + lm;
#pragma unroll
        for (int kc = 0; kc < 2; ++kc) {
            float v[8];
#pragma unroll
            for (int j = 0; j < 8; ++j) {
                int yy = kc * 32 + lg * 8 + j;
                v[j] = (yy < 50 && xx < 50) ? pb[yy * 50 + xx] : 0.f;
            }
            uint4 qh, ql;
            split2(v[0], v[1], qh.x, ql.x);
            split2(v[2], v[3], qh.y, ql.y);
            split2(v[4], v[5], qh.z, ql.z);
            split2(v[6], v[7], qh.w, ql.w);
            Bh[xt][kc] = *(bf16x8*)&qh; Bl[xt][kc] = *(bf16x8*)&ql;
        }
    }
    const f32x4 z4 = {0.f, 0.f, 0.f, 0.f};
    // step1 (this block's oyt): Q[oy][x] = sum_y M0[oy][y] P[y][x] -> LDS (intra-wave)
    {
        bf16x8 Ah[2], Al[2];
#pragma unroll
        for (int kc = 0; kc < 2; ++kc) {
            Ah[kc] = *(const bf16x8*)(MA + (((size_t)(0 * 6 + e) * 4 + oyt) * 2 + kc) * 512 + l * 8);
            Al[kc] = *(const bf16x8*)(MA + (((size_t)(1 * 6 + e) * 4 + oyt) * 2 + kc) * 512 + l * 8);
        }
#pragma unroll
        for (int xt = 0; xt < 4; ++xt) {
            f32x4 acc = z4;
#pragma unroll
            for (int kc = 0; kc < 2; ++kc) {
                acc = __builtin_amdgcn_mfma_f32_16x16x32_bf16(Ah[kc], Bh[xt][kc], acc, 0, 0, 0);
                acc = __builtin_amdgcn_mfma_f32_16x16x32_bf16(Ah[kc], Bl[xt][kc], acc, 0, 0, 0);
                acc = __builtin_amdgcn_mfma_f32_16x16x32_bf16(Al[kc], Bh[xt][kc], acc, 0, 0, 0);
            }
#pragma unroll
            for (int i = 0; i < 4; ++i) {
                int oy = oyt * 16 + lg * 4 + i;
                int xx = xt * 16 + lm;
                float qv = acc[i];
                unsigned u = __float_as_uint(qv);
                int off = offA2(oy, xx);
                Qhi[off] = (unsigned short)(u >> 16);
                float lo = qv - __uint_as_float(u & 0xffff0000u);
                Qlo[off] = (unsigned short)(__float_as_uint(lo) >> 16);
            }
        }
    }
    __builtin_amdgcn_wave_barrier();
    asm volatile("s_waitcnt lgkmcnt(0)" ::: "memory");
    __builtin_amdgcn_sched_barrier(0);
    // step2: R[oy][ox] = sum_x Q[oy][x] M1[ox][x] (scaled) -> X1 bf16, + global max
    float mmax = 0.f;
    unsigned short* xb = X1 + ((size_t)b * 125000 + (size_t)z * 2500) * 8 + e;
    bf16x8 Qh[2], Ql[2];
#pragma unroll
    for (int kc = 0; kc < 2; ++kc) {
        Qh[kc] = *(const bf16x8*)(Qhi + (kc * 64 + l) * 8);
        Ql[kc] = *(const bf16x8*)(Qlo + (kc * 64 + l) * 8);
    }
#pragma unroll
    for (int oxt = 0; oxt < 4; ++oxt) {
        f32x4 acc = z4;
#pragma unroll
        for (int kc = 0; kc < 2; ++kc) {
            bf16x8 mh = *(const bf16x8*)(MB + (((size_t)(0 * 6 + e) * 4 + oxt) * 2 + kc) * 512 + l * 8);
            bf16x8 ml = *(const bf16x8*)(MB + (((size_t)(1 * 6 + e) * 4 + oxt) * 2 + kc) * 512 + l * 8);
            acc = __builtin_amdgcn_mfma_f32_16x16x32_bf16(Qh[kc], mh, acc, 0, 0, 0);
            acc = __builtin_amdgcn_mfma_f32_16x16x32_bf16(Qh[kc], ml, acc, 0, 0, 0);
            acc = __builtin_amdgcn_mfma_f32_16x16x32_bf16(Ql[kc], mh, acc, 0, 0, 0);
        }
        int ox = oxt * 16 + lm;
        if (ox < 50) {
#pragma unroll
            for (int i = 0; i < 4; ++i) {
                int oy = oyt * 16 + lg * 4 + i;
                if (oy < 50) {
                    float rv = acc[i];
                    xb[((size_t)oy * 50 + ox) * 8] = f2bf(rv);
                    mmax = fmaxf(mmax, rv);
                }
            }
        }
    }
    for (int o = 32; o; o >>= 1) mmax = fmaxf(mmax, __shfl_xor(mmax, o));
    if (l == 0) atomicMax((int*)maxval, __float_as_int(mmax));
}

// ---------------- merged weight prep: wp1 (4-xsel), wp2, wp3 ----------------
__global__ void wprep_all(const float* __restrict__ W1c, const float* __restrict__ W2c,
                          const float* __restrict__ W3c,
                          unsigned short* __restrict__ wp1, unsigned short* __restrict__ wp2,
                          unsigned short* __restrict__ wp3) {
    int idx = blockIdx.x * 256 + threadIdx.x;
    const int N1 = 2 * 9 * 64;            // 1152
    const int N2 = 4 * 27 * 1 * 64;       // 6912
    const int N3 = 8 * 27 * 2 * 64;       // 27648
    if (idx < N1) {
        int l = idx & 63;
        int r = idx >> 6;
        int tg = r % 9, cog = r / 9;
        int xsel = l >> 4;
        int co = cog * 16 + (l & 15);
        unsigned short v[8];
#pragma unroll
        for (int j = 0; j < 8; ++j) {
            float wv = 0.f;
            if (j < 6 && xsel < 3) wv = W1c[((size_t)co * 6 + j) * 27 + tg * 3 + xsel];
            v[j] = f2bf(wv);
        }
        ((uint4*)wp1)[idx] = pack8(v);
        return;
    }
    idx -= N1;
    if (idx < N2) {
        int l = idx & 63;
        int r = idx >> 6;
        int tap = r % 27, cog = r / 27;
        int co = cog * 16 + (l & 15);
        unsigned short v[8];
#pragma unroll
        for (int j = 0; j < 8; ++j) {
            int ci = (l >> 4) * 8 + j;
            v[j] = f2bf(W2c[((size_t)co * 32 + ci) * 27 + tap]);
        }
        ((uint4*)wp2)[idx] = pack8(v);
        return;
    }
    idx -= N2;
    if (idx < N3) {
        int l = idx & 63;
        int r = idx >> 6;
        int ch = r % 2; r /= 2;
        int tap = r % 27;
        int cog = r / 27;
        int co = cog * 16 + (l & 15);
        unsigned short v[8];
#pragma unroll
        for (int j = 0; j < 8; ++j) {
            int ci = ch * 32 + (l >> 4) * 8 + j;
            v[j] = f2bf(W3c[((size_t)co * 64 + ci) * 27 + tap]);
        }
        ((uint4*)wp3)[idx] = pack8(v);
    }
}

// ---------------- conv1 MFMA: X1[50^3][8] -> X2[24^3][32], /max + bias + pool + relu ----------------
__global__ __launch_bounds__(64, 3)
void conv1_mfma(const unsigned short* __restrict__ X8, const unsigned short* __restrict__ wp1,
                const float* __restrict__ bias, const float* __restrict__ maxval,
                unsigned short* __restrict__ X2) {
    const int l = threadIdx.x, lm = l & 15, lg = l >> 4;
    const int q = (int)(gridDim.x >> 3);
    const int bid = ((int)blockIdx.x & 7) * q + ((int)blockIdx.x >> 3);
    const int s0 = bid * 8;
    const int r0 = s0 / 72;                 // uniform in block (8 | 72)
    const int cog = r0 % 2;
    const int pz  = (r0 / 2) % 24;
    const int b   = r0 / 48;
    uint4 B9[9];
    const uint4* wpb = (const uint4*)wp1 + cog * 9 * 64;
#pragma unroll
    for (int t = 0; t < 9; ++t) B9[t] = wpb[t * 64 + l];
    const float rmv = 1.0f / (*maxval);
    const float bia = bias[cog * 16 + lm];
    const unsigned short* Xb = X8 + (size_t)b * 125000 * 8;
    const f32x4 z4 = {0.f, 0.f, 0.f, 0.f};
#pragma unroll 1
    for (int si = 0; si < 8; ++si) {
        const int sid = s0 + si;
        const int xs = sid % 3;
        const int py = (sid / 3) % 24;
        const int x0 = xs * 16;
        f32x4 acc[2][2];
#pragma unroll
        for (int cz = 0; cz < 2; ++cz)
#pragma unroll
            for (int cy = 0; cy < 2; ++cy) acc[cz][cy] = z4;
#pragma unroll
        for (int zi = 0; zi < 4; ++zi) {
            const int zin = 2 * pz + zi;
#pragma unroll
            for (int yi = 0; yi < 4; ++yi) {
                const int yin = 2 * py + yi;
                const unsigned short* rowb = Xb + (size_t)(zin * 50 + yin) * 50 * 8;
                bf16x8 a = *(const bf16x8*)(rowb + (x0 + lm + lg) * 8);
#pragma unroll
                for (int cz = 0; cz < 2; ++cz) {
                    const int kz = zi - cz;
                    if (kz < 0 || kz > 2) continue;
#pragma unroll
                    for (int cy = 0; cy < 2; ++cy) {
                        const int ky = yi - cy;
                        if (ky < 0 || ky > 2) continue;
                        acc[cz][cy] = __builtin_amdgcn_mfma_f32_16x16x32_bf16(
                            a, *(const bf16x8*)&B9[kz * 3 + ky], acc[cz][cy], 0, 0, 0);
                    }
                }
            }
        }
        const int co = cog * 16 + lm;
#pragma unroll
        for (int ip = 0; ip < 2; ++ip) {
            float m0 = fmaxf(fmaxf(acc[0][0][2 * ip], acc[0][1][2 * ip]),
                             fmaxf(acc[1][0][2 * ip], acc[1][1][2 * ip]));
            float m1 = fmaxf(fmaxf(acc[0][0][2 * ip + 1], acc[0][1][2 * ip + 1]),
                             fmaxf(acc[1][0][2 * ip + 1], acc[1][1][2 * ip + 1]));
            float o = fmaxf(fmaxf(m0, m1) * rmv + bia, 0.f);
            int px = x0 / 2 + lg * 2 + ip;
            X2[((((size_t)b * 24 + pz) * 24 + py) * 24 + px) * 32 + co] = f2bf(o);
        }
    }
}

// ---------------- generic MFMA conv (conv2/conv3): bias + pool + relu -> bf16 ch-last ----------------
template <int DIN, int DP, int CI, int NCH, int NCOG, int NPY, int NXS, int SPB, int NPZ>
__global__ __launch_bounds__(64, 3)
void convN_mfma(const unsigned short* __restrict__ X, const unsigned short* __restrict__ wp,
                const float* __restrict__ bias, unsigned short* __restrict__ Y, int COUT) {
    const int l = threadIdx.x, lm = l & 15, lg = l >> 4;
    const int qq = (int)(gridDim.x >> 3);
    const int bid = ((int)blockIdx.x & 7) * qq + ((int)blockIdx.x >> 3);
    const int s0 = bid * SPB;
    const int r0 = s0 / (NPY * NXS);        // uniform in block
    const int cog = r0 % NCOG;
    const int pz  = (r0 / NCOG) % NPZ;
    const int b   = r0 / (NCOG * NPZ);
    const float bia = bias[cog * 16 + lm];
    const unsigned short* Xb = X + (size_t)b * DIN * DIN * DIN * CI;
    const uint4* wp4 = (const uint4*)wp;
    const f32x4 z4 = {0.f, 0.f, 0.f, 0.f};
#pragma unroll 1
    for (int si = 0; si < SPB; ++si) {
        const int sid = s0 + si;
        const int xs = sid % NXS;
        const int py = (sid / NXS) % NPY;
        const int x0 = xs * 16;
        int xo[3];
#pragma unroll
        for (int kx = 0; kx < 3; ++kx) {
            int xin = x0 + kx + lm;
            if (xin > DIN - 1) xin = DIN - 1;     // garbage rows masked at store
            xo[kx] = xin * CI + lg * 8;
        }
        f32x4 acc[2][2];
#pragma unroll
        for (int cz = 0; cz < 2; ++cz)
#pragma unroll
            for (int cy = 0; cy < 2; ++cy) acc[cz][cy] = z4;
#pragma unroll 1
        for (int ch = 0; ch < NCH; ++ch) {
            uint4 B[27];
            const uint4* wpb = wp4 + ((size_t)cog * 27 * NCH + ch) * 64;
#pragma unroll
            for (int t = 0; t < 27; ++t) B[t] = wpb[(size_t)t * NCH * 64 + l];
            const unsigned short* Xc = Xb + ch * 32;
#pragma unroll
            for (int zi = 0; zi < 4; ++zi) {
                const int zin = 2 * pz + zi;
#pragma unroll
                for (int yi = 0; yi < 4; ++yi) {
                    const int yin = 2 * py + yi;
                    const unsigned short* rowb = Xc + (size_t)(zin * DIN + yin) * DIN * CI;
#pragma unroll
                    for (int kx = 0; kx < 3; ++kx) {
                        bf16x8 a = *(const bf16x8*)(rowb + xo[kx]);
#pragma unroll
                        for (int cz = 0; cz < 2; ++cz) {
                            const int kz = zi - cz;
                            if (kz < 0 || kz > 2) continue;
#pragma unroll
                            for (int cy = 0; cy < 2; ++cy) {
                                const int ky = yi - cy;
                                if (ky < 0 || ky > 2) continue;
                                const int tap = (kz * 3 + ky) * 3 + kx;
                                acc[cz][cy] = __builtin_amdgcn_mfma_f32_16x16x32_bf16(
                                    a, *(const bf16x8*)&B[tap], acc[cz][cy], 0, 0, 0);
                            }
                        }
                    }
                }
            }
        }
        const int co = cog * 16 + lm;
#pragma unroll
        for (int ip = 0; ip < 2; ++ip) {
            float m0 = fmaxf(fmaxf(acc[0][0][2 * ip], acc[0][1][2 * ip]),
                             fmaxf(acc[1][0][2 * ip], acc[1][1][2 * ip]));
            float m1 = fmaxf(fmaxf(acc[0][0][2 * ip + 1], acc[0][1][2 * ip + 1]),
                             fmaxf(acc[1][0][2 * ip + 1], acc[1][1][2 * ip + 1]));
            float o = fmaxf(fmaxf(m0, m1) + bia, 0.f);
            int px = x0 / 2 + lg * 2 + ip;
            if (px < DP)
                Y[((((size_t)b * DP + pz) * DP + py) * DP + px) * COUT + co] = f2bf(o);
        }
    }
}

// ---------------- conv4: channels-last bf16 in, fp32 weights; wave per (b,co) ----------------
__global__ void conv4_kernel(const unsigned short* __restrict__ X4, const float* __restrict__ w,
                             const float* __restrict__ bias, float* __restrict__ out) {
    int wid = (int)((blockIdx.x * blockDim.x + threadIdx.x) >> 6);
    int lane = threadIdx.x & 63;
    if (wid >= NB * 256) return;
    int b = wid >> 8, co = wid & 255;
    float acc[8];
#pragma unroll
    for (int i = 0; i < 8; ++i) acc[i] = 0.f;
    for (int half = 0; half < 2; ++half) {
        int ci = lane + half * 64;
        float win[64];
#pragma unroll
        for (int v = 0; v < 64; ++v)
            win[v] = bf2f(X4[((size_t)b * 64 + v) * 128 + ci]);
        const float* wc = w + ((size_t)co * 128 + ci) * 27;
        float wr[27];
#pragma unroll
        for (int i = 0; i < 27; ++i) wr[i] = wc[i];
#pragma unroll
        for (int kz = 0; kz < 3; ++kz)
#pragma unroll
            for (int ky = 0; ky < 3; ++ky)
#pragma unroll
                for (int kx = 0; kx < 3; ++kx) {
                    float wv = wr[(kz * 3 + ky) * 3 + kx];
#pragma unroll
                    for (int oz = 0; oz < 2; ++oz)
#pragma unroll
                        for (int oy = 0; oy < 2; ++oy)
#pragma unroll
                            for (int ox = 0; ox < 2; ++ox)
                                acc[(oz * 2 + oy) * 2 + ox] =
                                    fmaf(wv, win[((oz + kz) * 4 + (oy + ky)) * 4 + ox + kx],
                                         acc[(oz * 2 + oy) * 2 + ox]);
                }
    }
#pragma unroll
    for (int o = 32; o; o >>= 1)
#pragma unroll
        for (int i = 0; i < 8; ++i) acc[i] += __shfl_xor(acc[i], o);
    if (lane == 0) {
        float m = acc[0];
#pragma unroll
        for (int i = 1; i < 8; ++i) m = fmaxf(m, acc[i]);
        out[(size_t)b * 256 + co] = fmaxf(m + bias[co], 0.f);
    }
}

// ---------------- FC head: (8,256) -> relu(128) -> 29 ----------------
__global__ void head_kernel(const float* __restrict__ v,
                            const float* __restrict__ fw1, const float* __restrict__ fb1,
                            const float* __restrict__ fw2, const float* __restrict__ fb2,
                            float* __restrict__ out) {
    int b = blockIdx.x, t = threadIdx.x;
    __shared__ float sv[256];
    __shared__ float s1[128];
    sv[t] = v[b * 256 + t];
    sv[t + 128] = v[b * 256 + t + 128];
    __syncthreads();
    float acc = fb1[t];
    const float* wr = fw1 + t * 256;
    for (int k = 0; k < 256; ++k) acc = fmaf(wr[k], sv[k], acc);
    s1[t] = fmaxf(acc, 0.f);
    __syncthreads();
    if (t < 29) {
        float a2 = fb2[t];
        const float* w2 = fw2 + t * 128;
        for (int k = 0; k < 128; ++k) a2 = fmaf(w2[k], s1[k], a2);
        out[b * 29 + t] = a2;
    }
}

extern "C" void kernel_launch(void* const* d_in, const int* in_sizes, int n_in,
                              void* d_out, int out_size, void* d_ws, size_t ws_size,
                              hipStream_t stream) {
    const float* x     = (const float*)d_in[0];
    const float* sigma = (const float*)d_in[1];
    const float* w1    = (const float*)d_in[2];
    const float* b1    = (const float*)d_in[3];
    const float* w2    = (const float*)d_in[4];
    const float* b2    = (const float*)d_in[5];
    const float* w3    = (const float*)d_in[6];
    const float* b3    = (const float*)d_in[7];
    const float* w4    = (const float*)d_in[8];
    const float* b4    = (const float*)d_in[9];
    const float* fw1   = (const float*)d_in[10];
    const float* fb1   = (const float*)d_in[11];
    const float* fw2   = (const float*)d_in[12];
    const float* fb2   = (const float*)d_in[13];
    float* out = (float*)d_out;

    // ---- workspace layout (~50 MB) ----
    float* W1 = (float*)d_ws;                                 // 6,000,000 f
    unsigned short* X1  = (unsigned short*)(W1 + NVOX);       // 8,000,064
    unsigned short* X2  = X1 + 8000064;                       // 3,538,944
    unsigned short* X3  = X2 + 3538944;                       // 681,472
    unsigned short* X4  = X3 + 681472;                        // 65,536
    unsigned short* wp1 = X4 + 65536;                         // 9,216
    unsigned short* wp2 = wp1 + 9216;                         // 55,296
    unsigned short* wp3 = wp2 + 55296;                        // 221,184
    unsigned short* MA  = wp3 + 221184;                       // 49,152
    unsigned short* MB  = MA + 49152;                         // 49,152
    float* mx = (float*)(MB + 49152);                         // 1
    float* v4 = mx + 1;                                       // 2,048 f

    taps_kernel<<<1, 512, 0, stream>>>(sigma, MA, MB, mx);

    // blur: K1 (z-axis, block = xt strip) then K2 (y+x, block = oyt) -> X1 bf16
    blur_k1<<<NB * NE * 50 * 4, 64, 0, stream>>>(x, W1, MA);
    blur_k2<<<NB * NE * 50 * 4, 64, 0, stream>>>(W1, MA, MB, X1, mx);

    // merged weight fragment packing (wp1+wp2+wp3)
    wprep_all<<<140, 256, 0, stream>>>(w1, w2, w3, wp1, wp2, wp3);

    // conv1: 4-xsel K-packing, XCD-swizzled
    conv1_mfma<<<3456, 64, 0, stream>>>(X1, wp1, b1, mx, X2);
    // conv2 / conv3 (XCD-swizzled inside)
    convN_mfma<24, 11, 32, 1, 4, 11, 2, 2, 11><<<3872, 64, 0, stream>>>(X2, wp2, b2, X3, 64);
    convN_mfma<11, 4, 64, 2, 8, 4, 1, 1, 4><<<1024, 64, 0, stream>>>(X3, wp3, b3, X4, 128);

    // conv4 (VALU, channels-last bf16 in) + head
    conv4_kernel<<<512, 256, 0, stream>>>(X4, w4, b4, v4);
    head_kernel<<<8, 128, 0, stream>>>(v4, fw1, fb1, fw2, fb2, out);
}

// Round 21
// 196.347 us; speedup vs baseline: 1.3721x; 1.3721x over previous
//
#include <hip/hip_runtime.h>
#include <math.h>

#define DIMX 50
#define KK   51
#define NE   6
#define NB   8
#define NVOX ((size_t)NB * NE * DIMX * DIMX * DIMX)  // 6,000,000

typedef short bf16x8 __attribute__((ext_vector_type(8)));
typedef float f32x4  __attribute__((ext_vector_type(4)));

__device__ __forceinline__ unsigned short f2bf(float f) {
    unsigned u = __float_as_uint(f);
    u += 0x7fffu + ((u >> 16) & 1u);      // RNE; inputs finite
    return (unsigned short)(u >> 16);
}
__device__ __forceinline__ float bf2f(unsigned short h) {
    return __uint_as_float((unsigned)h << 16);
}
__device__ __forceinline__ uint4 pack8(const unsigned short v[8]) {
    uint4 q;
    q.x = v[0] | ((unsigned)v[1] << 16);
    q.y = v[2] | ((unsigned)v[3] << 16);
    q.z = v[4] | ((unsigned)v[5] << 16);
    q.w = v[6] | ((unsigned)v[7] << 16);
    return q;
}
// truncation split of two floats -> packed hi-bf16 pair + lo-bf16 pair (6 VALU ops).
// hi = trunc(v) (AND); lo = v - hi (exact); lo packed by truncation too.
__device__ __forceinline__ void split2(float v0, float v1, unsigned& hp, unsigned& lp) {
    unsigned u0 = __float_as_uint(v0), u1 = __float_as_uint(v1);
    float h0 = __uint_as_float(u0 & 0xffff0000u);
    float h1 = __uint_as_float(u1 & 0xffff0000u);
    hp = __builtin_amdgcn_perm(u1, u0, 0x07060302u);
    lp = __builtin_amdgcn_perm(__float_as_uint(v1 - h1), __float_as_uint(v0 - h0), 0x07060302u);
}
// A-side fragment-linear offset: own=o(row), k; frag=((o>>4)*2+(k>>5)), lane=((k>>3)&3)*16+(o&15)
__device__ __forceinline__ int offA(int o, int k) {
    return ((((o >> 4) * 2 + (k >> 5)) * 64 + ((k >> 3) & 3) * 16 + (o & 15)) << 3) + (k & 7);
}

// -------- taps + MFMA-fragment-packed blur matrices --------
// MA[hl][e][t][kc][l][j]: A-side frags of RAW taps (own=o, k=z), val=tap[z-o+25]
// MB[hl][e][t][kc][l][j]: B-side frags of SCALED taps (own=ox, k=x), val=stap[x-ox+25]
__global__ void taps_kernel(const float* __restrict__ sigma,
                            unsigned short* __restrict__ MA, unsigned short* __restrict__ MB,
                            float* __restrict__ maxval) {
    __shared__ float sg[NE * KK];
    __shared__ float sgs[NE * KK];
    __shared__ float ssum[NE];
    int t = threadIdx.x;
    if (t == 0) *maxval = 0.f;
    if (t < NE * KK) {
        int e = t / KK, i = t % KK;
        float d = (float)i - 25.0f;
        float var = sigma[e] * sigma[e];
        sg[t] = expf(-d * d / (2.f * var));
    }
    __syncthreads();
    if (t < NE) {
        float s = 0.f;
        for (int i = 0; i < KK; ++i) s += sg[t * KK + i];
        ssum[t] = s;
    }
    __syncthreads();
    if (t < NE * KK) {
        int e = t / KK;
        float S = 0.f;
        for (int e2 = 0; e2 < NE; ++e2) {
            float var2 = sigma[e2] * sigma[e2];
            float a2 = 1.f / (2.f * (float)M_PI * var2);
            float se = ssum[e2];
            S += a2 * se * se * se;
        }
        float var = sigma[e] * sigma[e];
        float a = 1.f / (2.f * (float)M_PI * var);
        sgs[t] = sg[t] * (a / S);
    }
    __syncthreads();
    const int TOT = 2 * 6 * 4 * 2 * 64 * 8;   // 49152 per matrix
    for (int i = t; i < 2 * TOT; i += 512) {
        int which = i / TOT;                   // 0=MA(raw) 1=MB(scaled)
        int r = i % TOT;
        int q = r;
        int j = q & 7; q >>= 3;
        int l = q & 63; q >>= 6;
        int kc = q & 1; q >>= 1;
        int tile = q & 3; q >>= 2;
        int e = q % 6; q /= 6;
        int hl = q;                            // 0=hi 1=lo
        int own = tile * 16 + (l & 15);
        int k   = kc * 32 + ((l >> 4) << 3) + j;
        float v = 0.f;
        if (own < 50 && k < 50) {
            int d = k - own + 25;
            if (d >= 0 && d < KK) v = (which == 0 ? sg : sgs)[e * KK + d];
        }
        unsigned short h = f2bf(v);
        unsigned short out = (hl == 0) ? h : f2bf(v - bf2f(h));
        (which == 0 ? MA : MB)[r] = out;
    }
}

// -------- K1: z-axis blur via MFMA; 1-wave blocks, no LDS (B frags are lane-identity) --------
__global__ __launch_bounds__(64)
void blur_k1(const float* __restrict__ in, float* __restrict__ W1,
             const unsigned short* __restrict__ MA) {
    const int l = threadIdx.x, lm = l & 15, lg = l >> 4;
    const int y = blockIdx.x % 50, be = blockIdx.x / 50, e = be % 6;
    const float* pb = in + (size_t)be * 125000 + y * 50;
    bf16x8 Ah[4][2], Al[4][2];
#pragma unroll
    for (int ozt = 0; ozt < 4; ++ozt)
#pragma unroll
        for (int kc = 0; kc < 2; ++kc) {
            Ah[ozt][kc] = *(const bf16x8*)(MA + (((size_t)(0 * 6 + e) * 4 + ozt) * 2 + kc) * 512 + l * 8);
            Al[ozt][kc] = *(const bf16x8*)(MA + (((size_t)(1 * 6 + e) * 4 + ozt) * 2 + kc) * 512 + l * 8);
        }
    float* ob = W1 + (size_t)be * 125000 + y * 50;
    const f32x4 z4 = {0.f, 0.f, 0.f, 0.f};
#pragma unroll
    for (int xt = 0; xt < 4; ++xt) {
        const int xx = xt * 16 + lm;
        bf16x8 bh[2], bl[2];
#pragma unroll
        for (int kc = 0; kc < 2; ++kc) {
            float v[8];
#pragma unroll
            for (int j = 0; j < 8; ++j) {
                int z = kc * 32 + lg * 8 + j;
                v[j] = (z < 50 && xx < 50) ? pb[(size_t)z * 2500 + xx] : 0.f;
            }
            uint4 qh, ql;
            split2(v[0], v[1], qh.x, ql.x);
            split2(v[2], v[3], qh.y, ql.y);
            split2(v[4], v[5], qh.z, ql.z);
            split2(v[6], v[7], qh.w, ql.w);
            bh[kc] = *(bf16x8*)&qh; bl[kc] = *(bf16x8*)&ql;
        }
        f32x4 acc[4];
#pragma unroll
        for (int ozt = 0; ozt < 4; ++ozt) acc[ozt] = z4;
#pragma unroll
        for (int ozt = 0; ozt < 4; ++ozt)
#pragma unroll
            for (int kc = 0; kc < 2; ++kc) {
                acc[ozt] = __builtin_amdgcn_mfma_f32_16x16x32_bf16(Ah[ozt][kc], bh[kc], acc[ozt], 0, 0, 0);
                acc[ozt] = __builtin_amdgcn_mfma_f32_16x16x32_bf16(Ah[ozt][kc], bl[kc], acc[ozt], 0, 0, 0);
                acc[ozt] = __builtin_amdgcn_mfma_f32_16x16x32_bf16(Al[ozt][kc], bh[kc], acc[ozt], 0, 0, 0);
            }
        if (xx < 50) {
#pragma unroll
            for (int ozt = 0; ozt < 4; ++ozt)
#pragma unroll
                for (int i = 0; i < 4; ++i) {
                    int oz = ozt * 16 + lg * 4 + i;
                    if (oz < 50) ob[(size_t)oz * 2500 + xx] = acc[ozt][i];
                }
        }
    }
}

// -------- K2: fused y-blur + x-blur(scaled) + max; 1-wave blocks, intra-wave Q exchange --------
// Writes X1 bf16 8-pack directly. Grid logical order [(b,z)][e] with bijective XCD swizzle
// so all 6 e-blocks of a (b,z) share one XCD (L2 merges the 2B-interleaved X1 writes).
__global__ __launch_bounds__(64)
void blur_k2(const float* __restrict__ W1, const unsigned short* __restrict__ MA,
             const unsigned short* __restrict__ MB, unsigned short* __restrict__ X1,
             float* __restrict__ maxval) {
    __shared__ unsigned short Qhi[4096], Qlo[4096];
    const int l = threadIdx.x, lm = l & 15, lg = (l >> 4);
    const int q8 = (int)(gridDim.x >> 3);
    const int logical = ((int)blockIdx.x & 7) * q8 + ((int)blockIdx.x >> 3);
    const int e = logical % 6, bz = logical / 6, z = bz % 50, b = bz / 50;
    const float* pb = W1 + (size_t)(b * 6 + e) * 125000 + (size_t)z * 2500;
    // full plane B fragments in registers
    bf16x8 Bh[4][2], Bl[4][2];
#pragma unroll
    for (int xt = 0; xt < 4; ++xt) {
        const int xx = xt * 16 + lm;
#pragma unroll
        for (int kc = 0; kc < 2; ++kc) {
            float v[8];
#pragma unroll
            for (int j = 0; j < 8; ++j) {
                int yy = kc * 32 + lg * 8 + j;
                v[j] = (yy < 50 && xx < 50) ? pb[yy * 50 + xx] : 0.f;
            }
            uint4 qh, ql;
            split2(v[0], v[1], qh.x, ql.x);
            split2(v[2], v[3], qh.y, ql.y);
            split2(v[4], v[5], qh.z, ql.z);
            split2(v[6], v[7], qh.w, ql.w);
            Bh[xt][kc] = *(bf16x8*)&qh; Bl[xt][kc] = *(bf16x8*)&ql;
        }
    }
    const f32x4 z4 = {0.f, 0.f, 0.f, 0.f};
    // step1: Q[oy][x] = sum_y M0[oy][y] P[y][x] -> LDS frags (intra-wave)
#pragma unroll
    for (int oyt = 0; oyt < 4; ++oyt) {
        bf16x8 Ah[2], Al[2];
#pragma unroll
        for (int kc = 0; kc < 2; ++kc) {
            Ah[kc] = *(const bf16x8*)(MA + (((size_t)(0 * 6 + e) * 4 + oyt) * 2 + kc) * 512 + l * 8);
            Al[kc] = *(const bf16x8*)(MA + (((size_t)(1 * 6 + e) * 4 + oyt) * 2 + kc) * 512 + l * 8);
        }
#pragma unroll
        for (int xt = 0; xt < 4; ++xt) {
            f32x4 acc = z4;
#pragma unroll
            for (int kc = 0; kc < 2; ++kc) {
                acc = __builtin_amdgcn_mfma_f32_16x16x32_bf16(Ah[kc], Bh[xt][kc], acc, 0, 0, 0);
                acc = __builtin_amdgcn_mfma_f32_16x16x32_bf16(Ah[kc], Bl[xt][kc], acc, 0, 0, 0);
                acc = __builtin_amdgcn_mfma_f32_16x16x32_bf16(Al[kc], Bh[xt][kc], acc, 0, 0, 0);
            }
#pragma unroll
            for (int i = 0; i < 4; ++i) {
                int oy = oyt * 16 + lg * 4 + i;
                int xx = xt * 16 + lm;
                float qv = acc[i];
                unsigned u = __float_as_uint(qv);
                int off = offA(oy, xx);
                Qhi[off] = (unsigned short)(u >> 16);
                float lo = qv - __uint_as_float(u & 0xffff0000u);
                Qlo[off] = (unsigned short)(__float_as_uint(lo) >> 16);
            }
        }
    }
    __builtin_amdgcn_wave_barrier();
    asm volatile("s_waitcnt lgkmcnt(0)" ::: "memory");
    __builtin_amdgcn_sched_barrier(0);
    // step2: R[oy][ox] = sum_x Q[oy][x] M1[ox][x] (scaled) -> X1 bf16, + global max
    float mmax = 0.f;
    unsigned short* xb = X1 + ((size_t)b * 125000 + (size_t)z * 2500) * 8 + e;
#pragma unroll
    for (int oyt = 0; oyt < 4; ++oyt) {
        bf16x8 Qh[2], Ql[2];
#pragma unroll
        for (int kc = 0; kc < 2; ++kc) {
            Qh[kc] = *(const bf16x8*)(Qhi + ((oyt * 2 + kc) * 64 + l) * 8);
            Ql[kc] = *(const bf16x8*)(Qlo + ((oyt * 2 + kc) * 64 + l) * 8);
        }
#pragma unroll
        for (int oxt = 0; oxt < 4; ++oxt) {
            f32x4 acc = z4;
#pragma unroll
            for (int kc = 0; kc < 2; ++kc) {
                bf16x8 mh = *(const bf16x8*)(MB + (((size_t)(0 * 6 + e) * 4 + oxt) * 2 + kc) * 512 + l * 8);
                bf16x8 ml = *(const bf16x8*)(MB + (((size_t)(1 * 6 + e) * 4 + oxt) * 2 + kc) * 512 + l * 8);
                acc = __builtin_amdgcn_mfma_f32_16x16x32_bf16(Qh[kc], mh, acc, 0, 0, 0);
                acc = __builtin_amdgcn_mfma_f32_16x16x32_bf16(Qh[kc], ml, acc, 0, 0, 0);
                acc = __builtin_amdgcn_mfma_f32_16x16x32_bf16(Ql[kc], mh, acc, 0, 0, 0);
            }
            int ox = oxt * 16 + lm;
            if (ox < 50) {
#pragma unroll
                for (int i = 0; i < 4; ++i) {
                    int oy = oyt * 16 + lg * 4 + i;
                    if (oy < 50) {
                        float r = acc[i];
                        xb[((size_t)oy * 50 + ox) * 8] = f2bf(r);
                        mmax = fmaxf(mmax, r);
                    }
                }
            }
        }
    }
    for (int o = 32; o; o >>= 1) mmax = fmaxf(mmax, __shfl_xor(mmax, o));
    if (l == 0) atomicMax((int*)maxval, __float_as_int(mmax));
}

// ---------------- merged weight prep: wp1 (4-xsel), wp2, wp3 ----------------
__global__ void wprep_all(const float* __restrict__ W1c, const float* __restrict__ W2c,
                          const float* __restrict__ W3c,
                          unsigned short* __restrict__ wp1, unsigned short* __restrict__ wp2,
                          unsigned short* __restrict__ wp3) {
    int idx = blockIdx.x * 256 + threadIdx.x;
    const int N1 = 2 * 9 * 64;            // 1152
    const int N2 = 4 * 27 * 1 * 64;       // 6912
    const int N3 = 8 * 27 * 2 * 64;       // 27648
    if (idx < N1) {
        int l = idx & 63;
        int r = idx >> 6;
        int tg = r % 9, cog = r / 9;
        int xsel = l >> 4;
        int co = cog * 16 + (l & 15);
        unsigned short v[8];
#pragma unroll
        for (int j = 0; j < 8; ++j) {
            float wv = 0.f;
            if (j < 6 && xsel < 3) wv = W1c[((size_t)co * 6 + j) * 27 + tg * 3 + xsel];
            v[j] = f2bf(wv);
        }
        ((uint4*)wp1)[idx] = pack8(v);
        return;
    }
    idx -= N1;
    if (idx < N2) {
        int l = idx & 63;
        int r = idx >> 6;
        int tap = r % 27, cog = r / 27;
        int co = cog * 16 + (l & 15);
        unsigned short v[8];
#pragma unroll
        for (int j = 0; j < 8; ++j) {
            int ci = (l >> 4) * 8 + j;
            v[j] = f2bf(W2c[((size_t)co * 32 + ci) * 27 + tap]);
        }
        ((uint4*)wp2)[idx] = pack8(v);
        return;
    }
    idx -= N2;
    if (idx < N3) {
        int l = idx & 63;
        int r = idx >> 6;
        int ch = r % 2; r /= 2;
        int tap = r % 27;
        int cog = r / 27;
        int co = cog * 16 + (l & 15);
        unsigned short v[8];
#pragma unroll
        for (int j = 0; j < 8; ++j) {
            int ci = ch * 32 + (l >> 4) * 8 + j;
            v[j] = f2bf(W3c[((size_t)co * 64 + ci) * 27 + tap]);
        }
        ((uint4*)wp3)[idx] = pack8(v);
    }
}

// ---------------- conv1 MFMA: X1[50^3][8] -> X2[24^3][32], /max + bias + pool + relu ----------------
__global__ __launch_bounds__(64, 3)
void conv1_mfma(const unsigned short* __restrict__ X8, const unsigned short* __restrict__ wp1,
                const float* __restrict__ bias, const float* __restrict__ maxval,
                unsigned short* __restrict__ X2) {
    const int l = threadIdx.x, lm = l & 15, lg = l >> 4;
    const int q = (int)(gridDim.x >> 3);
    const int bid = ((int)blockIdx.x & 7) * q + ((int)blockIdx.x >> 3);
    const int s0 = bid * 8;
    const int r0 = s0 / 72;                 // uniform in block (8 | 72)
    const int cog = r0 % 2;
    const int pz  = (r0 / 2) % 24;
    const int b   = r0 / 48;
    uint4 B9[9];
    const uint4* wpb = (const uint4*)wp1 + cog * 9 * 64;
#pragma unroll
    for (int t = 0; t < 9; ++t) B9[t] = wpb[t * 64 + l];
    const float rmv = 1.0f / (*maxval);
    const float bia = bias[cog * 16 + lm];
    const unsigned short* Xb = X8 + (size_t)b * 125000 * 8;
    const f32x4 z4 = {0.f, 0.f, 0.f, 0.f};
#pragma unroll 1
    for (int si = 0; si < 8; ++si) {
        const int sid = s0 + si;
        const int xs = sid % 3;
        const int py = (sid / 3) % 24;
        const int x0 = xs * 16;
        f32x4 acc[2][2];
#pragma unroll
        for (int cz = 0; cz < 2; ++cz)
#pragma unroll
            for (int cy = 0; cy < 2; ++cy) acc[cz][cy] = z4;
#pragma unroll
        for (int zi = 0; zi < 4; ++zi) {
            const int zin = 2 * pz + zi;
#pragma unroll
            for (int yi = 0; yi < 4; ++yi) {
                const int yin = 2 * py + yi;
                const unsigned short* rowb = Xb + (size_t)(zin * 50 + yin) * 50 * 8;
                bf16x8 a = *(const bf16x8*)(rowb + (x0 + lm + lg) * 8);
#pragma unroll
                for (int cz = 0; cz < 2; ++cz) {
                    const int kz = zi - cz;
                    if (kz < 0 || kz > 2) continue;
#pragma unroll
                    for (int cy = 0; cy < 2; ++cy) {
                        const int ky = yi - cy;
                        if (ky < 0 || ky > 2) continue;
                        acc[cz][cy] = __builtin_amdgcn_mfma_f32_16x16x32_bf16(
                            a, *(const bf16x8*)&B9[kz * 3 + ky], acc[cz][cy], 0, 0, 0);
                    }
                }
            }
        }
        const int co = cog * 16 + lm;
#pragma unroll
        for (int ip = 0; ip < 2; ++ip) {
            float m0 = fmaxf(fmaxf(acc[0][0][2 * ip], acc[0][1][2 * ip]),
                             fmaxf(acc[1][0][2 * ip], acc[1][1][2 * ip]));
            float m1 = fmaxf(fmaxf(acc[0][0][2 * ip + 1], acc[0][1][2 * ip + 1]),
                             fmaxf(acc[1][0][2 * ip + 1], acc[1][1][2 * ip + 1]));
            float o = fmaxf(fmaxf(m0, m1) * rmv + bia, 0.f);
            int px = x0 / 2 + lg * 2 + ip;
            X2[((((size_t)b * 24 + pz) * 24 + py) * 24 + px) * 32 + co] = f2bf(o);
        }
    }
}

// ---------------- generic MFMA conv (conv2/conv3): bias + pool + relu -> bf16 ch-last ----------------
template <int DIN, int DP, int CI, int NCH, int NCOG, int NPY, int NXS, int SPB, int NPZ>
__global__ __launch_bounds__(64, 3)
void convN_mfma(const unsigned short* __restrict__ X, const unsigned short* __restrict__ wp,
                const float* __restrict__ bias, unsigned short* __restrict__ Y, int COUT) {
    const int l = threadIdx.x, lm = l & 15, lg = l >> 4;
    const int qq = (int)(gridDim.x >> 3);
    const int bid = ((int)blockIdx.x & 7) * qq + ((int)blockIdx.x >> 3);
    const int s0 = bid * SPB;
    const int r0 = s0 / (NPY * NXS);        // uniform in block
    const int cog = r0 % NCOG;
    const int pz  = (r0 / NCOG) % NPZ;
    const int b   = r0 / (NCOG * NPZ);
    const float bia = bias[cog * 16 + lm];
    const unsigned short* Xb = X + (size_t)b * DIN * DIN * DIN * CI;
    const uint4* wp4 = (const uint4*)wp;
    const f32x4 z4 = {0.f, 0.f, 0.f, 0.f};
#pragma unroll 1
    for (int si = 0; si < SPB; ++si) {
        const int sid = s0 + si;
        const int xs = sid % NXS;
        const int py = (sid / NXS) % NPY;
        const int x0 = xs * 16;
        int xo[3];
#pragma unroll
        for (int kx = 0; kx < 3; ++kx) {
            int xin = x0 + kx + lm;
            if (xin > DIN - 1) xin = DIN - 1;     // garbage rows masked at store
            xo[kx] = xin * CI + lg * 8;
        }
        f32x4 acc[2][2];
#pragma unroll
        for (int cz = 0; cz < 2; ++cz)
#pragma unroll
            for (int cy = 0; cy < 2; ++cy) acc[cz][cy] = z4;
#pragma unroll 1
        for (int ch = 0; ch < NCH; ++ch) {
            uint4 B[27];
            const uint4* wpb = wp4 + ((size_t)cog * 27 * NCH + ch) * 64;
#pragma unroll
            for (int t = 0; t < 27; ++t) B[t] = wpb[(size_t)t * NCH * 64 + l];
            const unsigned short* Xc = Xb + ch * 32;
#pragma unroll
            for (int zi = 0; zi < 4; ++zi) {
                const int zin = 2 * pz + zi;
#pragma unroll
                for (int yi = 0; yi < 4; ++yi) {
                    const int yin = 2 * py + yi;
                    const unsigned short* rowb = Xc + (size_t)(zin * DIN + yin) * DIN * CI;
#pragma unroll
                    for (int kx = 0; kx < 3; ++kx) {
                        bf16x8 a = *(const bf16x8*)(rowb + xo[kx]);
#pragma unroll
                        for (int cz = 0; cz < 2; ++cz) {
                            const int kz = zi - cz;
                            if (kz < 0 || kz > 2) continue;
#pragma unroll
                            for (int cy = 0; cy < 2; ++cy) {
                                const int ky = yi - cy;
                                if (ky < 0 || ky > 2) continue;
                                const int tap = (kz * 3 + ky) * 3 + kx;
                                acc[cz][cy] = __builtin_amdgcn_mfma_f32_16x16x32_bf16(
                                    a, *(const bf16x8*)&B[tap], acc[cz][cy], 0, 0, 0);
                            }
                        }
                    }
                }
            }
        }
        const int co = cog * 16 + lm;
#pragma unroll
        for (int ip = 0; ip < 2; ++ip) {
            float m0 = fmaxf(fmaxf(acc[0][0][2 * ip], acc[0][1][2 * ip]),
                             fmaxf(acc[1][0][2 * ip], acc[1][1][2 * ip]));
            float m1 = fmaxf(fmaxf(acc[0][0][2 * ip + 1], acc[0][1][2 * ip + 1]),
                             fmaxf(acc[1][0][2 * ip + 1], acc[1][1][2 * ip + 1]));
            float o = fmaxf(fmaxf(m0, m1) + bia, 0.f);
            int px = x0 / 2 + lg * 2 + ip;
            if (px < DP)
                Y[((((size_t)b * DP + pz) * DP + py) * DP + px) * COUT + co] = f2bf(o);
        }
    }
}

// ---------------- conv4: channels-last bf16 in, fp32 weights; wave per (b,co) ----------------
__global__ void conv4_kernel(const unsigned short* __restrict__ X4, const float* __restrict__ w,
                             const float* __restrict__ bias, float* __restrict__ out) {
    int wid = (int)((blockIdx.x * blockDim.x + threadIdx.x) >> 6);
    int lane = threadIdx.x & 63;
    if (wid >= NB * 256) return;
    int b = wid >> 8, co = wid & 255;
    float acc[8];
#pragma unroll
    for (int i = 0; i < 8; ++i) acc[i] = 0.f;
    for (int half = 0; half < 2; ++half) {
        int ci = lane + half * 64;
        float win[64];
#pragma unroll
        for (int v = 0; v < 64; ++v)
            win[v] = bf2f(X4[((size_t)b * 64 + v) * 128 + ci]);
        const float* wc = w + ((size_t)co * 128 + ci) * 27;
        float wr[27];
#pragma unroll
        for (int i = 0; i < 27; ++i) wr[i] = wc[i];
#pragma unroll
        for (int kz = 0; kz < 3; ++kz)
#pragma unroll
            for (int ky = 0; ky < 3; ++ky)
#pragma unroll
                for (int kx = 0; kx < 3; ++kx) {
                    float wv = wr[(kz * 3 + ky) * 3 + kx];
#pragma unroll
                    for (int oz = 0; oz < 2; ++oz)
#pragma unroll
                        for (int oy = 0; oy < 2; ++oy)
#pragma unroll
                            for (int ox = 0; ox < 2; ++ox)
                                acc[(oz * 2 + oy) * 2 + ox] =
                                    fmaf(wv, win[((oz + kz) * 4 + (oy + ky)) * 4 + ox + kx],
                                         acc[(oz * 2 + oy) * 2 + ox]);
                }
    }
#pragma unroll
    for (int o = 32; o; o >>= 1)
#pragma unroll
        for (int i = 0; i < 8; ++i) acc[i] += __shfl_xor(acc[i], o);
    if (lane == 0) {
        float m = acc[0];
#pragma unroll
        for (int i = 1; i < 8; ++i) m = fmaxf(m, acc[i]);
        out[(size_t)b * 256 + co] = fmaxf(m + bias[co], 0.f);
    }
}

// ---------------- FC head: (8,256) -> relu(128) -> 29 ----------------
__global__ void head_kernel(const float* __restrict__ v,
                            const float* __restrict__ fw1, const float* __restrict__ fb1,
                            const float* __restrict__ fw2, const float* __restrict__ fb2,
                            float* __restrict__ out) {
    int b = blockIdx.x, t = threadIdx.x;
    __shared__ float sv[256];
    __shared__ float s1[128];
    sv[t] = v[b * 256 + t];
    sv[t + 128] = v[b * 256 + t + 128];
    __syncthreads();
    float acc = fb1[t];
    const float* wr = fw1 + t * 256;
    for (int k = 0; k < 256; ++k) acc = fmaf(wr[k], sv[k], acc);
    s1[t] = fmaxf(acc, 0.f);
    __syncthreads();
    if (t < 29) {
        float a2 = fb2[t];
        const float* w2 = fw2 + t * 128;
        for (int k = 0; k < 128; ++k) a2 = fmaf(w2[k], s1[k], a2);
        out[b * 29 + t] = a2;
    }
}

extern "C" void kernel_launch(void* const* d_in, const int* in_sizes, int n_in,
                              void* d_out, int out_size, void* d_ws, size_t ws_size,
                              hipStream_t stream) {
    const float* x     = (const float*)d_in[0];
    const float* sigma = (const float*)d_in[1];
    const float* w1    = (const float*)d_in[2];
    const float* b1    = (const float*)d_in[3];
    const float* w2    = (const float*)d_in[4];
    const float* b2    = (const float*)d_in[5];
    const float* w3    = (const float*)d_in[6];
    const float* b3    = (const float*)d_in[7];
    const float* w4    = (const float*)d_in[8];
    const float* b4    = (const float*)d_in[9];
    const float* fw1   = (const float*)d_in[10];
    const float* fb1   = (const float*)d_in[11];
    const float* fw2   = (const float*)d_in[12];
    const float* fb2   = (const float*)d_in[13];
    float* out = (float*)d_out;

    // ---- workspace layout (~50 MB) ----
    float* W1 = (float*)d_ws;                                 // 6,000,000 f
    unsigned short* X1  = (unsigned short*)(W1 + NVOX);       // 8,000,064
    unsigned short* X2  = X1 + 8000064;                       // 3,538,944
    unsigned short* X3  = X2 + 3538944;                       // 681,472
    unsigned short* X4  = X3 + 681472;                        // 65,536
    unsigned short* wp1 = X4 + 65536;                         // 9,216
    unsigned short* wp2 = wp1 + 9216;                         // 55,296
    unsigned short* wp3 = wp2 + 55296;                        // 221,184
    unsigned short* MA  = wp3 + 221184;                       // 49,152
    unsigned short* MB  = MA + 49152;                         // 49,152
    float* mx = (float*)(MB + 49152);                         // 1
    float* v4 = mx + 1;                                       // 2,048 f

    taps_kernel<<<1, 512, 0, stream>>>(sigma, MA, MB, mx);

    // blur: K1 (z-axis, 1-wave, LDS-free) then K2 (y+x, 1-wave, scaled taps, max) -> X1 bf16
    blur_k1<<<NB * NE * 50, 64, 0, stream>>>(x, W1, MA);
    blur_k2<<<NB * NE * 50, 64, 0, stream>>>(W1, MA, MB, X1, mx);

    // merged weight fragment packing (wp1+wp2+wp3)
    wprep_all<<<140, 256, 0, stream>>>(w1, w2, w3, wp1, wp2, wp3);

    // conv1: 4-xsel K-packing, XCD-swizzled
    conv1_mfma<<<3456, 64, 0, stream>>>(X1, wp1, b1, mx, X2);
    // conv2 / conv3 (XCD-swizzled inside)
    convN_mfma<24, 11, 32, 1, 4, 11, 2, 2, 11><<<3872, 64, 0, stream>>>(X2, wp2, b2, X3, 64);
    convN_mfma<11, 4, 64, 2, 8, 4, 1, 1, 4><<<1024, 64, 0, stream>>>(X3, wp3, b3, X4, 128);

    // conv4 (VALU, channels-last bf16 in) + head
    conv4_kernel<<<512, 256, 0, stream>>>(X4, w4, b4, v4);
    head_kernel<<<8, 128, 0, stream>>>(v4, fw1, fb1, fw2, fb2, out);
}